// Round 8
// baseline (228.506 us; speedup 1.0000x reference)
//
#include <hip/hip_runtime.h>
#include <math.h>

#define SCALE_INV_SQRT_D 0.08838834764831844f   // 1/sqrt(128)

#define NQ 65536
#define NV 131072

typedef __attribute__((ext_vector_type(8))) short s16x8;
typedef __attribute__((ext_vector_type(4))) float f32x4;

__device__ __forceinline__ unsigned short f2bf(float f) {
    unsigned int u = __builtin_bit_cast(unsigned int, f);
    u += 0x7fffu + ((u >> 16) & 1u);          // round-to-nearest-even
    return (unsigned short)(u >> 16);
}
__device__ __forceinline__ float bf2f(unsigned short s) {
    return __builtin_bit_cast(float, (unsigned)s << 16);
}
#define LGKM0() asm volatile("s_waitcnt lgkmcnt(0)" ::: "memory")
#define SBAR0() __builtin_amdgcn_sched_barrier(0)

// k-slot permutation of the D-fragment layout (HW-verified R4/R5):
// slot (g,i) of a packed-D A-frag holds k = ks*32 + (i>=4)*16 + g*4 + (i&3).
__device__ __forceinline__ int kperm(int kk) {
    int i = kk & 7, gg = (kk >> 3) & 3, ks = kk >> 5;
    return (ks << 5) + ((i & 4) << 2) + (gg << 2) + (i & 3);
}

// ---------------------------------------------------------------------------
// prep: weights -> bf16, transposed to [N][K]; W2-like get kperm baked in.
// ---------------------------------------------------------------------------
__global__ __launch_bounds__(256) void prep_kernel(
    const float* __restrict__ qw1, const float* __restrict__ qw2,
    const float* __restrict__ vw1, const float* __restrict__ vw2,
    const float* __restrict__ sewr, const float* __restrict__ sewe,
    unsigned short* __restrict__ wbuf)
{
    int i = blockIdx.x * 256 + threadIdx.x;   // 163840 total
    float v;
    if (i < 32768)        { int li = i;          int n = li >> 7, k = li & 127;          v = qw1[k * 256 + n]; }
    else if (i < 65536)   { int li = i - 32768;  int n = li >> 8, k = kperm(li & 255);   v = qw2[k * 128 + n]; }
    else if (i < 98304)   { int li = i - 65536;  int n = li >> 7, k = li & 127;          v = vw1[k * 256 + n]; }
    else if (i < 131072)  { int li = i - 98304;  int n = li >> 8, k = kperm(li & 255);   v = vw2[k * 128 + n]; }
    else if (i < 147456)  { int li = i - 131072; int n = li >> 7, k = li & 127;          v = sewr[k * 128 + n]; }
    else                  { int li = i - 147456; int n = li >> 7, k = kperm(li & 127);   v = sewe[k * 128 + n]; }
    wbuf[i] = f2bf(v);
}

// ---------------------------------------------------------------------------
// se_gate: gate = sigmoid(relu(feat@se_wr+br)@se_we+be), stored PACKED in
// D-frag layout: gate_p[tile16*2048 + col*16 + (g*4+r)] (bf16). Coalesced.
// ---------------------------------------------------------------------------
__global__ __launch_bounds__(512, 4) void se_gate_kernel(
    const float* __restrict__ ctr_feat,
    const unsigned short* __restrict__ sewrt,  // [128][128]
    const float* __restrict__ sebr,
    const unsigned short* __restrict__ sewetp, // [128][128] k-permuted
    const float* __restrict__ sebe,
    unsigned short* __restrict__ gate_p)
{
    __shared__ __attribute__((aligned(16))) char s_w[65536];
    const int t = threadIdx.x;
    for (int c = t; c < 4096; c += 512) {
        int b  = c * 16;
        int lb = b & 32767;
        int row = lb >> 8;
        int dst = (b & 32768) + (lb ^ ((row & 7) << 4));
        const unsigned short* src = (b < 32768) ? (sewrt + lb / 2) : (sewetp + (lb / 2));
        *(s16x8*)(s_w + dst) = *(const s16x8*)src;
    }
    __syncthreads();

    const int lane = t & 63, wid = t >> 6;
    const int r16 = lane & 15, g = lane >> 4;
    const int swz = (r16 & 7) << 4;
    const int w  = blockIdx.x * 8 + wid;         // tile32 id (4096 total)
    const int s0 = w * 32;

    s16x8 fb[2][4];
    #pragma unroll
    for (int gr = 0; gr < 2; ++gr) {
        const int samp = s0 + gr * 16 + r16;
        #pragma unroll
        for (int ks = 0; ks < 4; ++ks) {
            const float* src = ctr_feat + (size_t)samp * 128 + ks * 32 + g * 8;
            f32x4 v0 = *(const f32x4*)(src);
            f32x4 v1 = *(const f32x4*)(src + 4);
            s16x8 pk;
            #pragma unroll
            for (int e = 0; e < 4; ++e) {
                pk[e]     = (short)f2bf(v0[e]);
                pk[4 + e] = (short)f2bf(v1[e]);
            }
            fb[gr][ks] = pk;
        }
    }
    s16x8 ga[2][4];
    #pragma unroll
    for (int u = 0; u < 4; ++u) {
        f32x4 a0[2], a1[2];
        #pragma unroll
        for (int gr = 0; gr < 2; ++gr) { a0[gr] = (f32x4)0.f; a1[gr] = (f32x4)0.f; }
        #pragma unroll
        for (int ks = 0; ks < 4; ++ks) {
            s16x8 w0 = *(const s16x8*)(s_w + ((((2 * u) * 16 + r16) * 256 + ks * 64 + g * 16) ^ swz));
            s16x8 w1 = *(const s16x8*)(s_w + ((((2 * u + 1) * 16 + r16) * 256 + ks * 64 + g * 16) ^ swz));
            #pragma unroll
            for (int gr = 0; gr < 2; ++gr) {
                a0[gr] = __builtin_amdgcn_mfma_f32_16x16x32_bf16(w0, fb[gr][ks], a0[gr], 0, 0, 0);
                a1[gr] = __builtin_amdgcn_mfma_f32_16x16x32_bf16(w1, fb[gr][ks], a1[gr], 0, 0, 0);
            }
        }
        f32x4 bb0 = *(const f32x4*)(sebr + 32 * u + g * 4);
        f32x4 bb1 = *(const f32x4*)(sebr + 32 * u + 16 + g * 4);
        #pragma unroll
        for (int gr = 0; gr < 2; ++gr) {
            s16x8 pk;
            #pragma unroll
            for (int r = 0; r < 4; ++r) {
                pk[r]     = (short)f2bf(fmaxf(a0[gr][r] + bb0[r], 0.f));
                pk[4 + r] = (short)f2bf(fmaxf(a1[gr][r] + bb1[r], 0.f));
            }
            ga[gr][u] = pk;
        }
    }
    #pragma unroll
    for (int n = 0; n < 8; ++n) {
        f32x4 acc[2] = {(f32x4)0.f, (f32x4)0.f};
        #pragma unroll
        for (int u = 0; u < 4; ++u) {
            s16x8 b = *(const s16x8*)(s_w + 32768 + (((n * 16 + r16) * 256 + u * 64 + g * 16) ^ swz));
            #pragma unroll
            for (int gr = 0; gr < 2; ++gr)
                acc[gr] = __builtin_amdgcn_mfma_f32_16x16x32_bf16(ga[gr][u], b, acc[gr], 0, 0, 0);
        }
        const int col = n * 16 + r16;
        const float bev = sebe[col];
        #pragma unroll
        for (int gr = 0; gr < 2; ++gr) {
            unsigned short pk[4];
            #pragma unroll
            for (int r = 0; r < 4; ++r)
                pk[r] = f2bf(1.0f / (1.0f + __expf(-(acc[gr][r] + bev))));
            *(unsigned long long*)(gate_p + (size_t)(2 * w + gr) * 2048 + col * 16 + g * 4)
                = *(const unsigned long long*)pk;
        }
    }
}

// ---------------------------------------------------------------------------
// pe_mlp: MLP(pos2posemb2d(p)), weights in 128KB LDS + per-wave 4KB
// transpose-staging buffer (total 160KiB). Epilogue: scatter 2B into LDS
// (XOR g<<5, conflict-free), then coalesced 16B/lane global stores.
// __launch_bounds__(512, 2): VGPR cap 256 — the ~230-reg live set
// (ape 32 + ha 64 + c2all 64 + gk 32 + addr) MUST NOT spill (R7 post-mortem:
// cap 128 caused scratch spills = the 83us / MfmaUtil 7% mystery).
// ---------------------------------------------------------------------------
template<bool GATE>
__global__ __launch_bounds__(512, 2) void pe_mlp_kernel(
    const float* __restrict__ ref_pts,
    const int*   __restrict__ ctr_coor,
    const unsigned short* __restrict__ w1t,   // [256][128]
    const float* __restrict__ b1,
    const unsigned short* __restrict__ w2tp,  // [128][256] k-permuted
    const float* __restrict__ b2,
    const unsigned short* __restrict__ gate_p,
    unsigned short* __restrict__ outb,        // rows x 128 bf16
    int ntile32)
{
    __shared__ __attribute__((aligned(16))) char s_w[131072 + 32768];
    const int t = threadIdx.x;
    for (int c = t; c < 8192; c += 512) {
        int b = c * 16;
        if (b < 65536) {
            int row = b >> 8;
            *(s16x8*)(s_w + (b ^ ((row & 7) << 4))) = *(const s16x8*)(w1t + b / 2);
        } else {
            int lb = b - 65536;
            int row = lb >> 9;
            *(s16x8*)(s_w + 65536 + (lb ^ ((row & 7) << 4))) = *(const s16x8*)(w2tp + lb / 2);
        }
    }
    __syncthreads();

    const int lane = t & 63, wid = t >> 6;
    const int r16 = lane & 15, g = lane >> 4;
    const int swz = (r16 & 7) << 4;
    char* s_out = s_w + 131072 + wid * 4096;   // per-wave 16x128 bf16 stage

    // hoisted per-col bias (col = n*16 + r16)
    float b2v[8];
    #pragma unroll
    for (int n = 0; n < 8; ++n) b2v[n] = b2[n * 16 + r16];

    for (int w = blockIdx.x * 8 + wid; w < ntile32; w += gridDim.x * 8) {
        const int s0 = w * 32;

        // pe B-frags, fully in-lane (positions in revolutions)
        s16x8 ape[2][4];
        #pragma unroll
        for (int gr = 0; gr < 2; ++gr) {
            const int samp = s0 + gr * 16 + r16;
            float xx, yy;
            if (GATE) {
                xx = ((float)ctr_coor[samp * 3 + 1] + 0.5f) * 0.2f;
                yy = ((float)ctr_coor[samp * 3 + 2] + 0.5f) * 0.2f;
            } else {
                xx = ref_pts[samp * 3 + 1];
                yy = ref_pts[samp * 3 + 2];
            }
            const float pnx = (xx + 51.2f) * (1.0f / 102.4f);
            const float pny = (yy + 51.2f) * (1.0f / 102.4f);
            #pragma unroll
            for (int ks = 0; ks < 4; ++ks) {
                const float p = (ks < 2) ? pny : pnx;
                s16x8 pk;
                #pragma unroll
                for (int j = 0; j < 4; ++j) {
                    float fr  = (float)(ks * 16 + g * 4 + j);
                    float rev = p * __builtin_exp2f(fr * -0.41524101186092029f);
                    float sn, cs;
                    asm("v_sin_f32 %0, %1" : "=v"(sn) : "v"(rev));
                    asm("v_cos_f32 %0, %1" : "=v"(cs) : "v"(rev));
                    pk[2 * j]     = (short)f2bf(sn);
                    pk[2 * j + 1] = (short)f2bf(cs);
                }
                ape[gr][ks] = pk;
            }
        }

        // GEMM1: h^T tiles -> packed GEMM2 A-frags
        s16x8 ha[2][8];
        #pragma unroll
        for (int u = 0; u < 8; ++u) {
            f32x4 a0[2], a1[2];
            #pragma unroll
            for (int gr = 0; gr < 2; ++gr) { a0[gr] = (f32x4)0.f; a1[gr] = (f32x4)0.f; }
            #pragma unroll
            for (int ks = 0; ks < 4; ++ks) {
                s16x8 w0 = *(const s16x8*)(s_w + ((((2 * u) * 16 + r16) * 256 + ks * 64 + g * 16) ^ swz));
                s16x8 w1 = *(const s16x8*)(s_w + ((((2 * u + 1) * 16 + r16) * 256 + ks * 64 + g * 16) ^ swz));
                #pragma unroll
                for (int gr = 0; gr < 2; ++gr) {
                    a0[gr] = __builtin_amdgcn_mfma_f32_16x16x32_bf16(w0, ape[gr][ks], a0[gr], 0, 0, 0);
                    a1[gr] = __builtin_amdgcn_mfma_f32_16x16x32_bf16(w1, ape[gr][ks], a1[gr], 0, 0, 0);
                }
            }
            f32x4 bb0 = *(const f32x4*)(b1 + 32 * u + g * 4);
            f32x4 bb1 = *(const f32x4*)(b1 + 32 * u + 16 + g * 4);
            #pragma unroll
            for (int gr = 0; gr < 2; ++gr) {
                s16x8 pk;
                #pragma unroll
                for (int r = 0; r < 4; ++r) {
                    pk[r]     = (short)f2bf(fmaxf(a0[gr][r] + bb0[r], 0.f));
                    pk[4 + r] = (short)f2bf(fmaxf(a1[gr][r] + bb1[r], 0.f));
                }
                ha[gr][u] = pk;
            }
        }

        // issue gate loads early (hide HBM latency under GEMM2)
        unsigned long long gk[2][8];
        if (GATE) {
            #pragma unroll
            for (int gr = 0; gr < 2; ++gr)
                #pragma unroll
                for (int n = 0; n < 8; ++n)
                    gk[gr][n] = *(const unsigned long long*)(
                        gate_p + (size_t)(2 * w + gr) * 2048 + (n * 16 + r16) * 16 + g * 4);
        }

        // GEMM2 (K=256), all n kept in regs
        f32x4 c2all[2][8];
        #pragma unroll
        for (int n = 0; n < 8; ++n) {
            f32x4 c0 = (f32x4)0.f, c1 = (f32x4)0.f;
            #pragma unroll
            for (int u = 0; u < 8; ++u) {
                s16x8 b = *(const s16x8*)(s_w + 65536 + (((n * 16 + r16) * 512 + u * 64 + g * 16) ^ swz));
                c0 = __builtin_amdgcn_mfma_f32_16x16x32_bf16(ha[0][u], b, c0, 0, 0, 0);
                c1 = __builtin_amdgcn_mfma_f32_16x16x32_bf16(ha[1][u], b, c1, 0, 0, 0);
            }
            c2all[0][n] = c0;
            c2all[1][n] = c1;
        }

        // epilogue: per gr, scatter -> s_out (swizzled) -> coalesced store
        #pragma unroll
        for (int gr = 0; gr < 2; ++gr) {
            #pragma unroll
            for (int n = 0; n < 8; ++n) {
                #pragma unroll
                for (int r = 0; r < 4; ++r) {
                    float v = c2all[gr][n][r] + b2v[n];
                    if (GATE) {
                        unsigned long long q = gk[gr][n];
                        v *= bf2f((unsigned short)(q >> (16 * r)));
                    }
                    *(unsigned short*)(s_out + (g * 4 + r) * 256 + ((n * 32 + r16 * 2) ^ (g << 5)))
                        = f2bf(v);
                }
            }
            LGKM0(); SBAR0();
            const int rrow = lane >> 2;
            #pragma unroll
            for (int it = 0; it < 4; ++it) {
                int cb = (lane & 3) * 64 + it * 16;
                s16x8 val = *(const s16x8*)(s_out + rrow * 256 + (cb ^ (((rrow >> 2) & 3) << 5)));
                *(s16x8*)((char*)outb + (size_t)(s0 + gr * 16 + rrow) * 256 + cb) = val;
            }
            LGKM0(); SBAR0();   // WAR: readback done before next scatter
        }
    }
}

// ---------------------------------------------------------------------------
// attention: one wave per query; qpos/vposg bf16, feat f32. (unchanged)
// ---------------------------------------------------------------------------
__global__ __launch_bounds__(256) void attn_kernel(
    const float* __restrict__ ref_pts,
    const unsigned short* __restrict__ qpos,
    const unsigned short* __restrict__ vposg,
    const float* __restrict__ ctr_feat,
    float* __restrict__ out)
{
    const int lane = threadIdx.x & 63;
    const int qi   = blockIdx.x * 4 + (threadIdx.x >> 6);

    const int   b = (int)ref_pts[qi * 3 + 0];
    const float x = ref_pts[qi * 3 + 1];
    const float y = ref_pts[qi * 3 + 2];
    const int xi = (int)(floorf(x / 0.2f) * 0.5f + 128.0f);
    const int yi = (int)(floorf(y / 0.2f) * 0.5f + 128.0f);

    const unsigned qp = *(const unsigned*)(qpos + (size_t)qi * 128 + lane * 2);
    const float qx = bf2f((unsigned short)(qp & 0xffffu));
    const float qy = bf2f((unsigned short)(qp >> 16));

    float  sc[9];
    float2 fv[9];
    #pragma unroll
    for (int n = 0; n < 9; ++n) {
        const int nx = xi + n / 3 - 1;
        const int ny = yi + n % 3 - 1;
        const bool valid = ((unsigned)nx < 256u) && ((unsigned)ny < 256u);
        float  s = 0.f;
        float2 f = {0.f, 0.f};
        if (valid) {
            const int idx = (b << 16) + (nx << 8) + ny;
            const unsigned vp = *(const unsigned*)(vposg + (size_t)idx * 128 + lane * 2);
            f = *(const float2*)(ctr_feat + (size_t)idx * 128 + lane * 2);
            s = qx * bf2f((unsigned short)(vp & 0xffffu)) + qy * bf2f((unsigned short)(vp >> 16));
        }
        sc[n] = s;
        fv[n] = f;
    }

    #pragma unroll
    for (int off = 32; off > 0; off >>= 1) {
        #pragma unroll
        for (int n = 0; n < 9; ++n)
            sc[n] += __shfl_xor(sc[n], off, 64);
    }

    float m = -1e30f;
    #pragma unroll
    for (int n = 0; n < 9; ++n) {
        sc[n] *= SCALE_INV_SQRT_D;
        m = fmaxf(m, sc[n]);
    }
    float e[9], denom = 0.f;
    #pragma unroll
    for (int n = 0; n < 9; ++n) {
        e[n] = __expf(sc[n] - m);
        denom += e[n];
    }
    const float inv = 1.0f / denom;

    float2 o = {0.f, 0.f};
    #pragma unroll
    for (int n = 0; n < 9; ++n) {
        const float w = e[n] * inv;
        o.x += w * fv[n].x;
        o.y += w * fv[n].y;
    }
    *(float2*)(out + (size_t)qi * 128 + lane * 2) = o;
}

extern "C" void kernel_launch(void* const* d_in, const int* in_sizes, int n_in,
                              void* d_out, int out_size, void* d_ws, size_t ws_size,
                              hipStream_t stream) {
    const float* ref_pts  = (const float*)d_in[0];
    const int*   ctr_coor = (const int*)d_in[1];
    const float* ctr_feat = (const float*)d_in[2];
    const float* q_w1 = (const float*)d_in[3];
    const float* q_b1 = (const float*)d_in[4];
    const float* q_w2 = (const float*)d_in[5];
    const float* q_b2 = (const float*)d_in[6];
    const float* v_w1 = (const float*)d_in[7];
    const float* v_b1 = (const float*)d_in[8];
    const float* v_w2 = (const float*)d_in[9];
    const float* v_b2 = (const float*)d_in[10];
    const float* se_wr = (const float*)d_in[11];
    const float* se_br = (const float*)d_in[12];
    const float* se_we = (const float*)d_in[13];
    const float* se_be = (const float*)d_in[14];

    unsigned short* wbuf   = (unsigned short*)d_ws;                  // 163840
    unsigned short* vposg  = wbuf + 163840;                          // NV*128 bf16
    unsigned short* qposb  = vposg + (size_t)NV * 128;               // NQ*128 bf16
    unsigned short* gate_p = qposb + (size_t)NQ * 128;               // NV*128 bf16

    const unsigned short* qw1t   = wbuf;
    const unsigned short* qw2tp  = wbuf + 32768;
    const unsigned short* vw1t   = wbuf + 65536;
    const unsigned short* vw2tp  = wbuf + 98304;
    const unsigned short* sewrt  = wbuf + 131072;
    const unsigned short* sewetp = wbuf + 147456;

    prep_kernel<<<640, 256, 0, stream>>>(q_w1, q_w2, v_w1, v_w2, se_wr, se_we, wbuf);

    se_gate_kernel<<<512, 512, 0, stream>>>(
        ctr_feat, sewrt, se_br, sewetp, se_be, gate_p);

    pe_mlp_kernel<false><<<256, 512, 0, stream>>>(
        ref_pts, nullptr, qw1t, q_b1, qw2tp, q_b2, nullptr, qposb, NQ / 32);

    pe_mlp_kernel<true><<<256, 512, 0, stream>>>(
        nullptr, ctr_coor, vw1t, v_b1, vw2tp, v_b2, gate_p, vposg, NV / 32);

    attn_kernel<<<NQ / 4, 256, 0, stream>>>(
        ref_pts, qposb, vposg, ctr_feat, (float*)d_out);
}

// Round 9
// 205.265 us; speedup vs baseline: 1.1132x; 1.1132x over previous
//
#include <hip/hip_runtime.h>
#include <math.h>

#define SCALE_INV_SQRT_D 0.08838834764831844f   // 1/sqrt(128)

#define NQ 65536
#define NV 131072

typedef __attribute__((ext_vector_type(8))) short s16x8;
typedef __attribute__((ext_vector_type(4))) float f32x4;

__device__ __forceinline__ unsigned short f2bf(float f) {
    unsigned int u = __builtin_bit_cast(unsigned int, f);
    u += 0x7fffu + ((u >> 16) & 1u);          // round-to-nearest-even
    return (unsigned short)(u >> 16);
}
__device__ __forceinline__ float bf2f(unsigned short s) {
    return __builtin_bit_cast(float, (unsigned)s << 16);
}
#define LGKM0() asm volatile("s_waitcnt lgkmcnt(0)" ::: "memory")
#define SBAR0() __builtin_amdgcn_sched_barrier(0)

// k-slot permutation of the D-fragment layout (HW-verified R4/R5):
// slot (g,i) of a packed-D A-frag holds k = ks*32 + (i>=4)*16 + g*4 + (i&3).
__device__ __forceinline__ int kperm(int kk) {
    int i = kk & 7, gg = (kk >> 3) & 3, ks = kk >> 5;
    return (ks << 5) + ((i & 4) << 2) + (gg << 2) + (i & 3);
}

// ---------------------------------------------------------------------------
// prep: weights -> bf16, transposed to [N][K]; W2-like get kperm baked in.
// ---------------------------------------------------------------------------
__global__ __launch_bounds__(256) void prep_kernel(
    const float* __restrict__ qw1, const float* __restrict__ qw2,
    const float* __restrict__ vw1, const float* __restrict__ vw2,
    const float* __restrict__ sewr, const float* __restrict__ sewe,
    unsigned short* __restrict__ wbuf)
{
    int i = blockIdx.x * 256 + threadIdx.x;   // 163840 total
    float v;
    if (i < 32768)        { int li = i;          int n = li >> 7, k = li & 127;          v = qw1[k * 256 + n]; }
    else if (i < 65536)   { int li = i - 32768;  int n = li >> 8, k = kperm(li & 255);   v = qw2[k * 128 + n]; }
    else if (i < 98304)   { int li = i - 65536;  int n = li >> 7, k = li & 127;          v = vw1[k * 256 + n]; }
    else if (i < 131072)  { int li = i - 98304;  int n = li >> 8, k = kperm(li & 255);   v = vw2[k * 128 + n]; }
    else if (i < 147456)  { int li = i - 131072; int n = li >> 7, k = li & 127;          v = sewr[k * 128 + n]; }
    else                  { int li = i - 147456; int n = li >> 7, k = kperm(li & 127);   v = sewe[k * 128 + n]; }
    wbuf[i] = f2bf(v);
}

// ---------------------------------------------------------------------------
// se_gate: gate = sigmoid(relu(feat@se_wr+br)@se_we+be), stored PACKED in
// D-frag layout: gate_p[tile16*2048 + col*16 + (g*4+r)] (bf16). Coalesced.
// ---------------------------------------------------------------------------
__global__ __launch_bounds__(512, 4) void se_gate_kernel(
    const float* __restrict__ ctr_feat,
    const unsigned short* __restrict__ sewrt,  // [128][128]
    const float* __restrict__ sebr,
    const unsigned short* __restrict__ sewetp, // [128][128] k-permuted
    const float* __restrict__ sebe,
    unsigned short* __restrict__ gate_p)
{
    __shared__ __attribute__((aligned(16))) char s_w[65536];
    const int t = threadIdx.x;
    for (int c = t; c < 4096; c += 512) {
        int b  = c * 16;
        int lb = b & 32767;
        int row = lb >> 8;
        int dst = (b & 32768) + (lb ^ ((row & 7) << 4));
        const unsigned short* src = (b < 32768) ? (sewrt + lb / 2) : (sewetp + (lb / 2));
        *(s16x8*)(s_w + dst) = *(const s16x8*)src;
    }
    __syncthreads();

    const int lane = t & 63, wid = t >> 6;
    const int r16 = lane & 15, g = lane >> 4;
    const int swz = (r16 & 7) << 4;
    const int w  = blockIdx.x * 8 + wid;         // tile32 id (4096 total)
    const int s0 = w * 32;

    s16x8 fb[2][4];
    #pragma unroll
    for (int gr = 0; gr < 2; ++gr) {
        const int samp = s0 + gr * 16 + r16;
        #pragma unroll
        for (int ks = 0; ks < 4; ++ks) {
            const float* src = ctr_feat + (size_t)samp * 128 + ks * 32 + g * 8;
            f32x4 v0 = *(const f32x4*)(src);
            f32x4 v1 = *(const f32x4*)(src + 4);
            s16x8 pk;
            #pragma unroll
            for (int e = 0; e < 4; ++e) {
                pk[e]     = (short)f2bf(v0[e]);
                pk[4 + e] = (short)f2bf(v1[e]);
            }
            fb[gr][ks] = pk;
        }
    }
    s16x8 ga[2][4];
    #pragma unroll
    for (int u = 0; u < 4; ++u) {
        f32x4 a0[2], a1[2];
        #pragma unroll
        for (int gr = 0; gr < 2; ++gr) { a0[gr] = (f32x4)0.f; a1[gr] = (f32x4)0.f; }
        #pragma unroll
        for (int ks = 0; ks < 4; ++ks) {
            s16x8 w0 = *(const s16x8*)(s_w + ((((2 * u) * 16 + r16) * 256 + ks * 64 + g * 16) ^ swz));
            s16x8 w1 = *(const s16x8*)(s_w + ((((2 * u + 1) * 16 + r16) * 256 + ks * 64 + g * 16) ^ swz));
            #pragma unroll
            for (int gr = 0; gr < 2; ++gr) {
                a0[gr] = __builtin_amdgcn_mfma_f32_16x16x32_bf16(w0, fb[gr][ks], a0[gr], 0, 0, 0);
                a1[gr] = __builtin_amdgcn_mfma_f32_16x16x32_bf16(w1, fb[gr][ks], a1[gr], 0, 0, 0);
            }
        }
        f32x4 bb0 = *(const f32x4*)(sebr + 32 * u + g * 4);
        f32x4 bb1 = *(const f32x4*)(sebr + 32 * u + 16 + g * 4);
        #pragma unroll
        for (int gr = 0; gr < 2; ++gr) {
            s16x8 pk;
            #pragma unroll
            for (int r = 0; r < 4; ++r) {
                pk[r]     = (short)f2bf(fmaxf(a0[gr][r] + bb0[r], 0.f));
                pk[4 + r] = (short)f2bf(fmaxf(a1[gr][r] + bb1[r], 0.f));
            }
            ga[gr][u] = pk;
        }
    }
    #pragma unroll
    for (int n = 0; n < 8; ++n) {
        f32x4 acc[2] = {(f32x4)0.f, (f32x4)0.f};
        #pragma unroll
        for (int u = 0; u < 4; ++u) {
            s16x8 b = *(const s16x8*)(s_w + 32768 + (((n * 16 + r16) * 256 + u * 64 + g * 16) ^ swz));
            #pragma unroll
            for (int gr = 0; gr < 2; ++gr)
                acc[gr] = __builtin_amdgcn_mfma_f32_16x16x32_bf16(ga[gr][u], b, acc[gr], 0, 0, 0);
        }
        const int col = n * 16 + r16;
        const float bev = sebe[col];
        #pragma unroll
        for (int gr = 0; gr < 2; ++gr) {
            unsigned short pk[4];
            #pragma unroll
            for (int r = 0; r < 4; ++r)
                pk[r] = f2bf(1.0f / (1.0f + __expf(-(acc[gr][r] + bev))));
            *(unsigned long long*)(gate_p + (size_t)(2 * w + gr) * 2048 + col * 16 + g * 4)
                = *(const unsigned long long*)pk;
        }
    }
}

// ---------------------------------------------------------------------------
// pe_mlp: MLP(pos2posemb2d(p)), weights in 128KB LDS + per-wave 4KB staging.
// R9: GEMM2 fused with epilogue per (gr,n) -> peak live VGPRs ~115 < 128 cap
// (R8 post-mortem: c2all[2][8]+gk[2][8] pushed live set to ~190 -> scratch
// spills = 45MB excess fetch AND write). Readback emits 1KB-contiguous
// stores per instruction (R7/R8 wrote 16B@stride-64B -> 64B-sector bloat).
// ---------------------------------------------------------------------------
template<bool GATE>
__global__ __launch_bounds__(512, 2) void pe_mlp_kernel(
    const float* __restrict__ ref_pts,
    const int*   __restrict__ ctr_coor,
    const unsigned short* __restrict__ w1t,   // [256][128]
    const float* __restrict__ b1,
    const unsigned short* __restrict__ w2tp,  // [128][256] k-permuted
    const float* __restrict__ b2,
    const unsigned short* __restrict__ gate_p,
    unsigned short* __restrict__ outb,        // rows x 128 bf16
    int ntile32)
{
    __shared__ __attribute__((aligned(16))) char s_w[131072 + 32768];
    const int t = threadIdx.x;
    for (int c = t; c < 8192; c += 512) {
        int b = c * 16;
        if (b < 65536) {
            int row = b >> 8;
            *(s16x8*)(s_w + (b ^ ((row & 7) << 4))) = *(const s16x8*)(w1t + b / 2);
        } else {
            int lb = b - 65536;
            int row = lb >> 9;
            *(s16x8*)(s_w + 65536 + (lb ^ ((row & 7) << 4))) = *(const s16x8*)(w2tp + lb / 2);
        }
    }
    __syncthreads();

    const int lane = t & 63, wid = t >> 6;
    const int r16 = lane & 15, g = lane >> 4;
    const int swz = (r16 & 7) << 4;
    char* s_out = s_w + 131072 + wid * 4096;   // per-wave 16x128 bf16 stage

    // hoisted per-col bias (col = n*16 + r16)
    float b2v[8];
    #pragma unroll
    for (int n = 0; n < 8; ++n) b2v[n] = b2[n * 16 + r16];

    for (int w = blockIdx.x * 8 + wid; w < ntile32; w += gridDim.x * 8) {
        const int s0 = w * 32;

        // pe B-frags, fully in-lane (positions in revolutions)
        s16x8 ape[2][4];
        #pragma unroll
        for (int gr = 0; gr < 2; ++gr) {
            const int samp = s0 + gr * 16 + r16;
            float xx, yy;
            if (GATE) {
                xx = ((float)ctr_coor[samp * 3 + 1] + 0.5f) * 0.2f;
                yy = ((float)ctr_coor[samp * 3 + 2] + 0.5f) * 0.2f;
            } else {
                xx = ref_pts[samp * 3 + 1];
                yy = ref_pts[samp * 3 + 2];
            }
            const float pnx = (xx + 51.2f) * (1.0f / 102.4f);
            const float pny = (yy + 51.2f) * (1.0f / 102.4f);
            #pragma unroll
            for (int ks = 0; ks < 4; ++ks) {
                const float p = (ks < 2) ? pny : pnx;
                s16x8 pk;
                #pragma unroll
                for (int j = 0; j < 4; ++j) {
                    float fr  = (float)(ks * 16 + g * 4 + j);
                    float rev = p * __builtin_exp2f(fr * -0.41524101186092029f);
                    float sn, cs;
                    asm("v_sin_f32 %0, %1" : "=v"(sn) : "v"(rev));
                    asm("v_cos_f32 %0, %1" : "=v"(cs) : "v"(rev));
                    pk[2 * j]     = (short)f2bf(sn);
                    pk[2 * j + 1] = (short)f2bf(cs);
                }
                ape[gr][ks] = pk;
            }
        }

        // GEMM1: h^T tiles -> packed GEMM2 A-frags
        s16x8 ha[2][8];
        #pragma unroll
        for (int u = 0; u < 8; ++u) {
            f32x4 a0[2], a1[2];
            #pragma unroll
            for (int gr = 0; gr < 2; ++gr) { a0[gr] = (f32x4)0.f; a1[gr] = (f32x4)0.f; }
            #pragma unroll
            for (int ks = 0; ks < 4; ++ks) {
                s16x8 w0 = *(const s16x8*)(s_w + ((((2 * u) * 16 + r16) * 256 + ks * 64 + g * 16) ^ swz));
                s16x8 w1 = *(const s16x8*)(s_w + ((((2 * u + 1) * 16 + r16) * 256 + ks * 64 + g * 16) ^ swz));
                #pragma unroll
                for (int gr = 0; gr < 2; ++gr) {
                    a0[gr] = __builtin_amdgcn_mfma_f32_16x16x32_bf16(w0, ape[gr][ks], a0[gr], 0, 0, 0);
                    a1[gr] = __builtin_amdgcn_mfma_f32_16x16x32_bf16(w1, ape[gr][ks], a1[gr], 0, 0, 0);
                }
            }
            f32x4 bb0 = *(const f32x4*)(b1 + 32 * u + g * 4);
            f32x4 bb1 = *(const f32x4*)(b1 + 32 * u + 16 + g * 4);
            #pragma unroll
            for (int gr = 0; gr < 2; ++gr) {
                s16x8 pk;
                #pragma unroll
                for (int r = 0; r < 4; ++r) {
                    pk[r]     = (short)f2bf(fmaxf(a0[gr][r] + bb0[r], 0.f));
                    pk[4 + r] = (short)f2bf(fmaxf(a1[gr][r] + bb1[r], 0.f));
                }
                ha[gr][u] = pk;
            }
        }

        // GEMM2 (K=256) fused with epilogue, per gr: live set stays < 128
        #pragma unroll
        for (int gr = 0; gr < 2; ++gr) {
            unsigned long long gk[8];
            if (GATE) {
                #pragma unroll
                for (int n = 0; n < 8; ++n)
                    gk[n] = *(const unsigned long long*)(
                        gate_p + (size_t)(2 * w + gr) * 2048 + (n * 16 + r16) * 16 + g * 4);
            }
            #pragma unroll
            for (int n = 0; n < 8; ++n) {
                f32x4 c = (f32x4)0.f;
                #pragma unroll
                for (int u = 0; u < 8; ++u) {
                    s16x8 b = *(const s16x8*)(s_w + 65536 + (((n * 16 + r16) * 512 + u * 64 + g * 16) ^ swz));
                    c = __builtin_amdgcn_mfma_f32_16x16x32_bf16(ha[gr][u], b, c, 0, 0, 0);
                }
                #pragma unroll
                for (int r = 0; r < 4; ++r) {
                    float v = c[r] + b2v[n];
                    if (GATE) v *= bf2f((unsigned short)(gk[n] >> (16 * r)));
                    *(unsigned short*)(s_out + (g * 4 + r) * 256 + ((n * 32 + r16 * 2) ^ (g << 5)))
                        = f2bf(v);
                }
            }
            LGKM0(); SBAR0();
            // coalesced readback: per it, 4 consecutive rows x 256B = 1KB contig
            #pragma unroll
            for (int it = 0; it < 4; ++it) {
                int row = it * 4 + (lane >> 4);
                int cb  = (lane & 15) * 16;
                s16x8 val = *(const s16x8*)(s_out + row * 256 + (cb ^ (((row >> 2) & 3) << 5)));
                *(s16x8*)((char*)outb + (size_t)(s0 + gr * 16 + row) * 256 + cb) = val;
            }
            LGKM0(); SBAR0();   // WAR: readback done before next scatter
        }
    }
}

// ---------------------------------------------------------------------------
// attention: one wave per query; qpos/vposg bf16, feat f32. (unchanged)
// ---------------------------------------------------------------------------
__global__ __launch_bounds__(256) void attn_kernel(
    const float* __restrict__ ref_pts,
    const unsigned short* __restrict__ qpos,
    const unsigned short* __restrict__ vposg,
    const float* __restrict__ ctr_feat,
    float* __restrict__ out)
{
    const int lane = threadIdx.x & 63;
    const int qi   = blockIdx.x * 4 + (threadIdx.x >> 6);

    const int   b = (int)ref_pts[qi * 3 + 0];
    const float x = ref_pts[qi * 3 + 1];
    const float y = ref_pts[qi * 3 + 2];
    const int xi = (int)(floorf(x / 0.2f) * 0.5f + 128.0f);
    const int yi = (int)(floorf(y / 0.2f) * 0.5f + 128.0f);

    const unsigned qp = *(const unsigned*)(qpos + (size_t)qi * 128 + lane * 2);
    const float qx = bf2f((unsigned short)(qp & 0xffffu));
    const float qy = bf2f((unsigned short)(qp >> 16));

    float  sc[9];
    float2 fv[9];
    #pragma unroll
    for (int n = 0; n < 9; ++n) {
        const int nx = xi + n / 3 - 1;
        const int ny = yi + n % 3 - 1;
        const bool valid = ((unsigned)nx < 256u) && ((unsigned)ny < 256u);
        float  s = 0.f;
        float2 f = {0.f, 0.f};
        if (valid) {
            const int idx = (b << 16) + (nx << 8) + ny;
            const unsigned vp = *(const unsigned*)(vposg + (size_t)idx * 128 + lane * 2);
            f = *(const float2*)(ctr_feat + (size_t)idx * 128 + lane * 2);
            s = qx * bf2f((unsigned short)(vp & 0xffffu)) + qy * bf2f((unsigned short)(vp >> 16));
        }
        sc[n] = s;
        fv[n] = f;
    }

    #pragma unroll
    for (int off = 32; off > 0; off >>= 1) {
        #pragma unroll
        for (int n = 0; n < 9; ++n)
            sc[n] += __shfl_xor(sc[n], off, 64);
    }

    float m = -1e30f;
    #pragma unroll
    for (int n = 0; n < 9; ++n) {
        sc[n] *= SCALE_INV_SQRT_D;
        m = fmaxf(m, sc[n]);
    }
    float e[9], denom = 0.f;
    #pragma unroll
    for (int n = 0; n < 9; ++n) {
        e[n] = __expf(sc[n] - m);
        denom += e[n];
    }
    const float inv = 1.0f / denom;

    float2 o = {0.f, 0.f};
    #pragma unroll
    for (int n = 0; n < 9; ++n) {
        const float w = e[n] * inv;
        o.x += w * fv[n].x;
        o.y += w * fv[n].y;
    }
    *(float2*)(out + (size_t)qi * 128 + lane * 2) = o;
}

extern "C" void kernel_launch(void* const* d_in, const int* in_sizes, int n_in,
                              void* d_out, int out_size, void* d_ws, size_t ws_size,
                              hipStream_t stream) {
    const float* ref_pts  = (const float*)d_in[0];
    const int*   ctr_coor = (const int*)d_in[1];
    const float* ctr_feat = (const float*)d_in[2];
    const float* q_w1 = (const float*)d_in[3];
    const float* q_b1 = (const float*)d_in[4];
    const float* q_w2 = (const float*)d_in[5];
    const float* q_b2 = (const float*)d_in[6];
    const float* v_w1 = (const float*)d_in[7];
    const float* v_b1 = (const float*)d_in[8];
    const float* v_w2 = (const float*)d_in[9];
    const float* v_b2 = (const float*)d_in[10];
    const float* se_wr = (const float*)d_in[11];
    const float* se_br = (const float*)d_in[12];
    const float* se_we = (const float*)d_in[13];
    const float* se_be = (const float*)d_in[14];

    unsigned short* wbuf   = (unsigned short*)d_ws;                  // 163840
    unsigned short* vposg  = wbuf + 163840;                          // NV*128 bf16
    unsigned short* qposb  = vposg + (size_t)NV * 128;               // NQ*128 bf16
    unsigned short* gate_p = qposb + (size_t)NQ * 128;               // NV*128 bf16

    const unsigned short* qw1t   = wbuf;
    const unsigned short* qw2tp  = wbuf + 32768;
    const unsigned short* vw1t   = wbuf + 65536;
    const unsigned short* vw2tp  = wbuf + 98304;
    const unsigned short* sewrt  = wbuf + 131072;
    const unsigned short* sewetp = wbuf + 147456;

    prep_kernel<<<640, 256, 0, stream>>>(q_w1, q_w2, v_w1, v_w2, se_wr, se_we, wbuf);

    se_gate_kernel<<<512, 512, 0, stream>>>(
        ctr_feat, sewrt, se_br, sewetp, se_be, gate_p);

    pe_mlp_kernel<false><<<256, 512, 0, stream>>>(
        ref_pts, nullptr, qw1t, q_b1, qw2tp, q_b2, nullptr, qposb, NQ / 32);

    pe_mlp_kernel<true><<<256, 512, 0, stream>>>(
        nullptr, ctr_coor, vw1t, v_b1, vw2tp, v_b2, gate_p, vposg, NV / 32);

    attn_kernel<<<NQ / 4, 256, 0, stream>>>(
        ref_pts, qposb, vposg, ctr_feat, (float*)d_out);
}